// Round 1
// baseline (766.386 us; speedup 1.0000x reference)
//
#include <hip/hip_runtime.h>
#include <hip/hip_bf16.h>

#define NTOK   256
#define DMODEL 512
#define NHEAD  8
#define HD     64
#define HALF   32
#define FF     1536
#define RCFF   2048
#define VOCAB  32000
#define NLAYER 2
#define NSTEPS 4
#define EPSV   1e-6f
#define THR    0.99f

// ---------------- embedding gather ----------------
__global__ void k_embed(const int* __restrict__ ids, const float* __restrict__ emb,
                        float* __restrict__ x) {
    int row = blockIdx.x;
    int id = ids[row];
    for (int d = threadIdx.x; d < DMODEL; d += blockDim.x)
        x[row * DMODEL + d] = emb[(size_t)id * DMODEL + d];
}

// ---------------- rmsnorm (one block per row) ----------------
__global__ __launch_bounds__(256) void k_rmsnorm(const float* __restrict__ in,
                                                 const float* __restrict__ w,
                                                 float* __restrict__ out) {
    int row = blockIdx.x;
    const float* xr = in + (size_t)row * DMODEL;
    float s = 0.f;
    for (int d = threadIdx.x; d < DMODEL; d += 256) { float v = xr[d]; s += v * v; }
    __shared__ float red[4];
    int lane = threadIdx.x & 63, wv = threadIdx.x >> 6;
    for (int o = 32; o > 0; o >>= 1) s += __shfl_xor(s, o);
    if (lane == 0) red[wv] = s;
    __syncthreads();
    float tot = red[0] + red[1] + red[2] + red[3];
    float scale = rsqrtf(tot * (1.f / DMODEL) + EPSV);
    for (int d = threadIdx.x; d < DMODEL; d += 256)
        out[(size_t)row * DMODEL + d] = xr[d] * scale * w[d];
}

// ---------------- split-K matmul partial: Cp[z][M][N] = A[:,kz:kz+kc] @ W[kz:kz+kc,:] ----
__global__ __launch_bounds__(256) void k_mm_part(const float* __restrict__ A,
                                                 const float* __restrict__ W,
                                                 float* __restrict__ Cp,
                                                 int K, int N, int kc) {
    __shared__ float As[16][68];
    __shared__ float Ws[16][68];
    const int bn = blockIdx.x * 64;
    const int bm = blockIdx.y * 64;
    const int kz = blockIdx.z * kc;
    const int tx = threadIdx.x & 15;
    const int ty = threadIdx.x >> 4;
    float acc[4][4] = {};
    for (int k0 = kz; k0 < kz + kc; k0 += 16) {
#pragma unroll
        for (int r = 0; r < 4; ++r) {
            int idx = threadIdx.x + r * 256;
            int m = idx >> 4, kk = idx & 15;
            As[kk][m] = A[(size_t)(bm + m) * K + k0 + kk];
            int n = idx & 63, kw = idx >> 6;
            Ws[kw][n] = W[(size_t)(k0 + kw) * N + bn + n];
        }
        __syncthreads();
#pragma unroll
        for (int kk = 0; kk < 16; ++kk) {
            float4 av = *(const float4*)&As[kk][ty * 4];
            float4 bv = *(const float4*)&Ws[kk][tx * 4];
            float a[4] = {av.x, av.y, av.z, av.w};
            float b[4] = {bv.x, bv.y, bv.z, bv.w};
#pragma unroll
            for (int i = 0; i < 4; ++i)
#pragma unroll
                for (int j = 0; j < 4; ++j)
                    acc[i][j] = fmaf(a[i], b[j], acc[i][j]);
        }
        __syncthreads();
    }
    float* cp = Cp + (size_t)blockIdx.z * (size_t)(gridDim.y * 64) * N;
#pragma unroll
    for (int i = 0; i < 4; ++i) {
        int m = bm + ty * 4 + i;
#pragma unroll
        for (int j = 0; j < 4; ++j)
            cp[(size_t)m * N + bn + tx * 4 + j] = acc[i][j];
    }
}

// ---------------- split-K reduce (+residual, +optional gelu) ----------------
__global__ void k_mm_finish(const float* __restrict__ Cp, const float* __restrict__ res,
                            float* __restrict__ C, int tot, int zstride, int nz, int act) {
    int i = blockIdx.x * 256 + threadIdx.x;
    if (i >= tot) return;
    float s = 0.f;
    for (int z = 0; z < nz; ++z) s += Cp[(size_t)z * zstride + i];
    if (res) s += res[i];
    if (act == 1) {  // gelu (tanh approx, jax default)
        float xg = s;
        float inner = 0.79788456080286536f * (xg + 0.044715f * xg * xg * xg);
        s = 0.5f * xg * (1.f + tanhf(inner));
    }
    C[i] = s;
}

// ---------------- split-K reduce for gate/up with silu(g)*u fusion ----------------
__global__ void k_finish_silumul(const float* __restrict__ Gp, const float* __restrict__ Up,
                                 float* __restrict__ C, int tot, int zstride, int nz) {
    int i = blockIdx.x * 256 + threadIdx.x;
    if (i >= tot) return;
    float g = 0.f, u = 0.f;
    for (int z = 0; z < nz; ++z) {
        g += Gp[(size_t)z * zstride + i];
        u += Up[(size_t)z * zstride + i];
    }
    float sig = 1.f / (1.f + expf(-g));
    C[i] = g * sig * u;
}

// ---------------- RoPE in-place on q,k halves of qkv ----------------
__global__ void k_rope(float* __restrict__ qkv) {
    int pos = blockIdx.x;
    int t = threadIdx.x;          // 256 = 8 heads * 32 pairs
    int h = t >> 5, d = t & 31;
    float inv = powf(10000.f, -(float)d / 32.f);
    float ang = (float)pos * inv;
    float c = cosf(ang), s = sinf(ang);
    float* q = qkv + (size_t)pos * FF + h * HD;
    float x1 = q[d], x2 = q[d + HALF];
    q[d] = x1 * c - x2 * s;
    q[d + HALF] = x1 * s + x2 * c;
    float* k = q + DMODEL;
    x1 = k[d]; x2 = k[d + HALF];
    k[d] = x1 * c - x2 * s;
    k[d + HALF] = x1 * s + x2 * c;
}

// ---------------- attention: one block per (head, query) ----------------
__global__ __launch_bounds__(256) void k_attn(const float* __restrict__ qkv,
                                              float* __restrict__ out) {
    int h = blockIdx.x;
    int qi = blockIdx.y;
    int t = threadIdx.x;
    __shared__ float qs[HD];
    __shared__ float ps[NTOK];
    __shared__ float red[4];
    __shared__ float red2[4];
    __shared__ float os[4][HD];
    if (t < HD) qs[t] = qkv[(size_t)qi * FF + h * HD + t];
    __syncthreads();
    float sc = -1e30f;
    if (t <= qi) {
        const float* kr = qkv + (size_t)t * FF + DMODEL + h * HD;
        float s = 0.f;
        for (int d = 0; d < HD; ++d) s = fmaf(qs[d], kr[d], s);
        sc = s * 0.125f;
    }
    float m = sc;
    for (int o = 32; o > 0; o >>= 1) m = fmaxf(m, __shfl_xor(m, o));
    int lane = t & 63, wv = t >> 6;
    if (lane == 0) red[wv] = m;
    __syncthreads();
    m = fmaxf(fmaxf(red[0], red[1]), fmaxf(red[2], red[3]));
    float e = (t <= qi) ? expf(sc - m) : 0.f;
    ps[t] = e;
    float sum = e;
    for (int o = 32; o > 0; o >>= 1) sum += __shfl_xor(sum, o);
    if (lane == 0) red2[wv] = sum;
    __syncthreads();
    sum = red2[0] + red2[1] + red2[2] + red2[3];
    float inv = 1.f / sum;
    int d = t & 63, g = t >> 6;
    float acc = 0.f;
    for (int ki = g; ki <= qi; ki += 4)
        acc = fmaf(ps[ki], qkv[(size_t)ki * FF + 2 * DMODEL + h * HD + d], acc);
    os[g][d] = acc * inv;
    __syncthreads();
    if (t < HD)
        out[(size_t)qi * DMODEL + h * HD + t] = os[0][t] + os[1][t] + os[2][t] + os[3][t];
}

// ---------------- halt logits: sigmoid(h . w_halt + b) ----------------
__global__ __launch_bounds__(64) void k_halt(const float* __restrict__ H,
                                             const float* __restrict__ w,
                                             const float* __restrict__ bptr,
                                             float* __restrict__ halt) {
    int s = blockIdx.y, row = blockIdx.x;
    const float* h = H + ((size_t)s * NTOK + row) * DMODEL;
    float acc = 0.f;
    for (int d = threadIdx.x; d < DMODEL; d += 64) acc = fmaf(h[d], w[d], acc);
    for (int o = 32; o > 0; o >>= 1) acc += __shfl_xor(acc, o);
    if (threadIdx.x == 0)
        halt[s * NTOK + row] = 1.f / (1.f + expf(-(acc + bptr[0])));
}

// ---------------- ACT combine weights + ponder ----------------
__global__ void k_act(const float* __restrict__ halt, float* __restrict__ wts,
                      float* __restrict__ ponder_out, float* __restrict__ w_out) {
    int i = threadIdx.x;  // 256 tokens, single block
    float p[4];
#pragma unroll
    for (int s = 0; s < 4; ++s) p[s] = halt[s * NTOK + i];
    p[0] = 0.f;  // MIN_STEPS = 1
    float cum = 0.f, rem = 0.f, w[4];
    int nrun = 0;
#pragma unroll
    for (int s = 0; s < 4; ++s) {
        float prev = cum;
        cum += p[s];
        bool running = prev < THR;
        bool use_rem = running && ((cum >= THR) || (s == 3));
        float v = 0.f;
        if (running) {
            v = use_rem ? (1.f - prev) : p[s];
            if (use_rem) rem += (1.f - prev);
            nrun++;
        }
        w[s] = v;
    }
#pragma unroll
    for (int s = 0; s < 4; ++s) { wts[i * 4 + s] = w[s]; w_out[i * 4 + s] = w[s]; }
    ponder_out[i] = (float)nrun + rem;
}

// ---------------- A = sum_s w_s * H_s ; B = sum_s w_s * H_{s+1} ----------------
__global__ void k_ab(const float* __restrict__ H, const float* __restrict__ wts,
                     float* __restrict__ A, float* __restrict__ Bm) {
    int i = blockIdx.x;
    float w0 = wts[i * 4 + 0], w1 = wts[i * 4 + 1], w2 = wts[i * 4 + 2], w3 = wts[i * 4 + 3];
    for (int d = threadIdx.x; d < DMODEL; d += 256) {
        size_t base = (size_t)i * DMODEL + d;
        float h0 = H[base], h1 = H[base + NTOK * DMODEL], h2 = H[base + 2 * NTOK * DMODEL];
        float h3 = H[base + 3 * (size_t)NTOK * DMODEL], h4 = H[base + 4 * (size_t)NTOK * DMODEL];
        A[base] = w0 * h0 + w1 * h1 + w2 * h2 + w3 * h3;
        Bm[base] = w0 * h1 + w1 * h2 + w2 * h3 + w3 * h4;
    }
}

// ---------------- final logits: out = A @ Wy + B @ Wd ----------------
__global__ __launch_bounds__(256) void k_logits(const float* __restrict__ A,
                                                const float* __restrict__ Bm,
                                                const float* __restrict__ Wy,
                                                const float* __restrict__ Wd,
                                                float* __restrict__ out) {
    __shared__ float As[16][68];
    __shared__ float Bs[16][68];
    __shared__ float Ys[16][68];
    __shared__ float Ds[16][68];
    const int bn = blockIdx.x * 64;
    const int bm = blockIdx.y * 64;
    const int tx = threadIdx.x & 15;
    const int ty = threadIdx.x >> 4;
    float acc[4][4] = {};
    for (int k0 = 0; k0 < DMODEL; k0 += 16) {
#pragma unroll
        for (int r = 0; r < 4; ++r) {
            int idx = threadIdx.x + r * 256;
            int m = idx >> 4, kk = idx & 15;
            As[kk][m] = A[(size_t)(bm + m) * DMODEL + k0 + kk];
            Bs[kk][m] = Bm[(size_t)(bm + m) * DMODEL + k0 + kk];
            int n = idx & 63, kw = idx >> 6;
            Ys[kw][n] = Wy[(size_t)(k0 + kw) * VOCAB + bn + n];
            Ds[kw][n] = Wd[(size_t)(k0 + kw) * VOCAB + bn + n];
        }
        __syncthreads();
#pragma unroll
        for (int kk = 0; kk < 16; ++kk) {
            float4 av = *(const float4*)&As[kk][ty * 4];
            float4 bv = *(const float4*)&Bs[kk][ty * 4];
            float4 yv = *(const float4*)&Ys[kk][tx * 4];
            float4 dv = *(const float4*)&Ds[kk][tx * 4];
            float a[4] = {av.x, av.y, av.z, av.w};
            float b[4] = {bv.x, bv.y, bv.z, bv.w};
            float y[4] = {yv.x, yv.y, yv.z, yv.w};
            float dd[4] = {dv.x, dv.y, dv.z, dv.w};
#pragma unroll
            for (int i = 0; i < 4; ++i)
#pragma unroll
                for (int j = 0; j < 4; ++j)
                    acc[i][j] = fmaf(a[i], y[j], fmaf(b[i], dd[j], acc[i][j]));
        }
        __syncthreads();
    }
#pragma unroll
    for (int i = 0; i < 4; ++i) {
        int m = bm + ty * 4 + i;
#pragma unroll
        for (int j = 0; j < 4; ++j)
            out[(size_t)m * VOCAB + bn + tx * 4 + j] = acc[i][j];
    }
}

extern "C" void kernel_launch(void* const* d_in, const int* in_sizes, int n_in,
                              void* d_out, int out_size, void* d_ws, size_t ws_size,
                              hipStream_t stream) {
    const int*   ids          = (const int*)d_in[0];
    const float* emb          = (const float*)d_in[1];
    const float* attn_norm_w  = (const float*)d_in[2];
    const float* mlp_norm_w   = (const float*)d_in[3];
    const float* wqkv         = (const float*)d_in[4];
    const float* wo           = (const float*)d_in[5];
    const float* w_gate       = (const float*)d_in[6];
    const float* w_up         = (const float*)d_in[7];
    const float* w_down       = (const float*)d_in[8];
    const float* final_norm_w = (const float*)d_in[9];
    const float* rc_norm_w    = (const float*)d_in[10];
    const float* rc_w1        = (const float*)d_in[11];
    const float* rc_w2        = (const float*)d_in[12];
    const float* w_y          = (const float*)d_in[13];
    const float* w_delta      = (const float*)d_in[14];
    const float* w_halt       = (const float*)d_in[15];
    const float* b_halt       = (const float*)d_in[16];
    float* out = (float*)d_out;

    float* ws = (float*)d_ws;
    float* x       = ws + 0;         // 131072
    float* xn      = ws + 131072;    // 131072
    float* qkv     = ws + 262144;    // 393216
    float* attnout = ws + 655360;    // 131072
    float* g       = ws + 786432;    // 393216
    float* t1      = ws + 1179648;   // 524288 (rc mlp intermediate; also Cp2 in backbone)
    float* states  = ws + 1703936;   // 131072
    float* states2 = ws + 1835008;   // 131072
    float* H       = ws + 1966080;   // 655360 (5 slices of 131072)
    float* haltb   = ws + 2621440;   // 1024
    float* wts     = ws + 2622464;   // 1024
    float* Abuf    = ws + 2623488;   // 131072
    float* Bbuf    = ws + 2754560;   // 131072
    float* Cp      = ws + 2885632;   // 2097152 (split-K partials, up to 4*256*2048)
    float* Cp2     = t1;             // alias: gate/up partials live only in backbone

    auto mm = [&](const float* A, const float* W, const float* res, float* C,
                  int K, int N, int nsplit, int act) {
        int kc = K / nsplit;
        k_mm_part<<<dim3(N / 64, NTOK / 64, nsplit), 256, 0, stream>>>(A, W, Cp, K, N, kc);
        int tot = NTOK * N;
        k_mm_finish<<<(tot + 255) / 256, 256, 0, stream>>>(Cp, res, C, tot, tot, nsplit, act);
    };

    // ---------- backbone ----------
    k_embed<<<NTOK, 256, 0, stream>>>(ids, emb, x);
    for (int l = 0; l < NLAYER; ++l) {
        k_rmsnorm<<<NTOK, 256, 0, stream>>>(x, attn_norm_w + l * DMODEL, xn);
        mm(xn, wqkv + (size_t)l * DMODEL * FF, nullptr, qkv, DMODEL, FF, 2, 0);
        k_rope<<<NTOK, 256, 0, stream>>>(qkv);
        k_attn<<<dim3(NHEAD, NTOK), 256, 0, stream>>>(qkv, attnout);
        mm(attnout, wo + (size_t)l * DMODEL * DMODEL, x, x, DMODEL, DMODEL, 2, 0);
        k_rmsnorm<<<NTOK, 256, 0, stream>>>(x, mlp_norm_w + l * DMODEL, xn);
        // gate and up partials, fused silu(g)*u reduce
        {
            int kc = DMODEL / 2;
            k_mm_part<<<dim3(FF / 64, NTOK / 64, 2), 256, 0, stream>>>(
                xn, w_gate + (size_t)l * DMODEL * FF, Cp, DMODEL, FF, kc);
            k_mm_part<<<dim3(FF / 64, NTOK / 64, 2), 256, 0, stream>>>(
                xn, w_up + (size_t)l * DMODEL * FF, Cp2, DMODEL, FF, kc);
            int tot = NTOK * FF;
            k_finish_silumul<<<(tot + 255) / 256, 256, 0, stream>>>(Cp, Cp2, g, tot, tot, 2);
        }
        mm(g, w_down + (size_t)l * FF * DMODEL, x, x, FF, DMODEL, 3, 0);
    }
    k_rmsnorm<<<NTOK, 256, 0, stream>>>(x, final_norm_w, states);

    // ---------- refinement steps (halt path stays f32) ----------
    float* scur = states;
    float* snxt = states2;
    for (int s = 0; s < NSTEPS; ++s) {
        k_rmsnorm<<<NTOK, 256, 0, stream>>>(scur, rc_norm_w, H + (size_t)s * NTOK * DMODEL);
        mm(H + (size_t)s * NTOK * DMODEL, rc_w1, nullptr, t1, DMODEL, RCFF, 2, 1);  // gelu fused
        mm(t1, rc_w2, scur, snxt, RCFF, DMODEL, 4, 0);
        float* tmp = scur; scur = snxt; snxt = tmp;
    }
    k_rmsnorm<<<NTOK, 256, 0, stream>>>(scur, rc_norm_w, H + (size_t)NSTEPS * NTOK * DMODEL);

    // ---------- halt, ACT weights, A/B combine ----------
    k_halt<<<dim3(NTOK, NSTEPS), 64, 0, stream>>>(H, w_halt, b_halt, haltb);
    k_act<<<1, 256, 0, stream>>>(haltb, wts, out + (size_t)NTOK * VOCAB,
                                 out + (size_t)NTOK * VOCAB + NTOK);
    k_ab<<<NTOK, 256, 0, stream>>>(H, wts, Abuf, Bbuf);

    // ---------- final logits ----------
    k_logits<<<dim3(VOCAB / 64, NTOK / 64), 256, 0, stream>>>(Abuf, Bbuf, w_y, w_delta, out);
}

// Round 2
// 656.313 us; speedup vs baseline: 1.1677x; 1.1677x over previous
//
#include <hip/hip_runtime.h>
#include <hip/hip_bf16.h>

#define NTOK   256
#define DMODEL 512
#define NHEAD  8
#define HD     64
#define HALF   32
#define FF     1536
#define RCFF   2048
#define VOCAB  32000
#define NLAYER 2
#define NSTEPS 4
#define EPSV   1e-6f
#define THR    0.99f

typedef __attribute__((ext_vector_type(8))) short bf16x8;
typedef __attribute__((ext_vector_type(4))) float f32x4;

// ---------------- embedding gather ----------------
__global__ void k_embed(const int* __restrict__ ids, const float* __restrict__ emb,
                        float* __restrict__ x) {
    int row = blockIdx.x;
    int id = ids[row];
    for (int d = threadIdx.x; d < DMODEL; d += blockDim.x)
        x[row * DMODEL + d] = emb[(size_t)id * DMODEL + d];
}

// ---------------- rmsnorm (one block per row) ----------------
__global__ __launch_bounds__(256) void k_rmsnorm(const float* __restrict__ in,
                                                 const float* __restrict__ w,
                                                 float* __restrict__ out) {
    int row = blockIdx.x;
    const float* xr = in + (size_t)row * DMODEL;
    float s = 0.f;
    for (int d = threadIdx.x; d < DMODEL; d += 256) { float v = xr[d]; s += v * v; }
    __shared__ float red[4];
    int lane = threadIdx.x & 63, wv = threadIdx.x >> 6;
    for (int o = 32; o > 0; o >>= 1) s += __shfl_xor(s, o);
    if (lane == 0) red[wv] = s;
    __syncthreads();
    float tot = red[0] + red[1] + red[2] + red[3];
    float scale = rsqrtf(tot * (1.f / DMODEL) + EPSV);
    for (int d = threadIdx.x; d < DMODEL; d += 256)
        out[(size_t)row * DMODEL + d] = xr[d] * scale * w[d];
}

// ---------------- split-K matmul partial ----------------
__global__ __launch_bounds__(256) void k_mm_part(const float* __restrict__ A,
                                                 const float* __restrict__ W,
                                                 float* __restrict__ Cp,
                                                 int K, int N, int kc) {
    __shared__ float As[16][68];
    __shared__ float Ws[16][68];
    const int bn = blockIdx.x * 64;
    const int bm = blockIdx.y * 64;
    const int kz = blockIdx.z * kc;
    const int tx = threadIdx.x & 15;
    const int ty = threadIdx.x >> 4;
    float acc[4][4] = {};
    for (int k0 = kz; k0 < kz + kc; k0 += 16) {
#pragma unroll
        for (int r = 0; r < 4; ++r) {
            int idx = threadIdx.x + r * 256;
            int m = idx >> 4, kk = idx & 15;
            As[kk][m] = A[(size_t)(bm + m) * K + k0 + kk];
            int n = idx & 63, kw = idx >> 6;
            Ws[kw][n] = W[(size_t)(k0 + kw) * N + bn + n];
        }
        __syncthreads();
#pragma unroll
        for (int kk = 0; kk < 16; ++kk) {
            float4 av = *(const float4*)&As[kk][ty * 4];
            float4 bv = *(const float4*)&Ws[kk][tx * 4];
            float a[4] = {av.x, av.y, av.z, av.w};
            float b[4] = {bv.x, bv.y, bv.z, bv.w};
#pragma unroll
            for (int i = 0; i < 4; ++i)
#pragma unroll
                for (int j = 0; j < 4; ++j)
                    acc[i][j] = fmaf(a[i], b[j], acc[i][j]);
        }
        __syncthreads();
    }
    float* cp = Cp + (size_t)blockIdx.z * (size_t)(gridDim.y * 64) * N;
#pragma unroll
    for (int i = 0; i < 4; ++i) {
        int m = bm + ty * 4 + i;
#pragma unroll
        for (int j = 0; j < 4; ++j)
            cp[(size_t)m * N + bn + tx * 4 + j] = acc[i][j];
    }
}

// ---------------- split-K reduce (+residual, +optional gelu) ----------------
__global__ void k_mm_finish(const float* __restrict__ Cp, const float* __restrict__ res,
                            float* __restrict__ C, int tot, int zstride, int nz, int act) {
    int i = blockIdx.x * 256 + threadIdx.x;
    if (i >= tot) return;
    float s = 0.f;
    for (int z = 0; z < nz; ++z) s += Cp[(size_t)z * zstride + i];
    if (res) s += res[i];
    if (act == 1) {  // gelu (tanh approx, jax default)
        float xg = s;
        float inner = 0.79788456080286536f * (xg + 0.044715f * xg * xg * xg);
        s = 0.5f * xg * (1.f + tanhf(inner));
    }
    C[i] = s;
}

// ---------------- split-K reduce for gate/up with silu(g)*u fusion ----------------
__global__ void k_finish_silumul(const float* __restrict__ Gp, const float* __restrict__ Up,
                                 float* __restrict__ C, int tot, int zstride, int nz) {
    int i = blockIdx.x * 256 + threadIdx.x;
    if (i >= tot) return;
    float g = 0.f, u = 0.f;
    for (int z = 0; z < nz; ++z) {
        g += Gp[(size_t)z * zstride + i];
        u += Up[(size_t)z * zstride + i];
    }
    float sig = 1.f / (1.f + expf(-g));
    C[i] = g * sig * u;
}

// ---------------- RoPE in-place on q,k halves of qkv ----------------
__global__ void k_rope(float* __restrict__ qkv) {
    int pos = blockIdx.x;
    int t = threadIdx.x;          // 256 = 8 heads * 32 pairs
    int h = t >> 5, d = t & 31;
    float inv = powf(10000.f, -(float)d / 32.f);
    float ang = (float)pos * inv;
    float c = cosf(ang), s = sinf(ang);
    float* q = qkv + (size_t)pos * FF + h * HD;
    float x1 = q[d], x2 = q[d + HALF];
    q[d] = x1 * c - x2 * s;
    q[d + HALF] = x1 * s + x2 * c;
    float* k = q + DMODEL;
    x1 = k[d]; x2 = k[d + HALF];
    k[d] = x1 * c - x2 * s;
    k[d + HALF] = x1 * s + x2 * c;
}

// ---------------- attention: one block per (head, query) ----------------
__global__ __launch_bounds__(256) void k_attn(const float* __restrict__ qkv,
                                              float* __restrict__ out) {
    int h = blockIdx.x;
    int qi = blockIdx.y;
    int t = threadIdx.x;
    __shared__ float qs[HD];
    __shared__ float ps[NTOK];
    __shared__ float red[4];
    __shared__ float red2[4];
    __shared__ float os[4][HD];
    if (t < HD) qs[t] = qkv[(size_t)qi * FF + h * HD + t];
    __syncthreads();
    float sc = -1e30f;
    if (t <= qi) {
        const float* kr = qkv + (size_t)t * FF + DMODEL + h * HD;
        float s = 0.f;
        for (int d = 0; d < HD; ++d) s = fmaf(qs[d], kr[d], s);
        sc = s * 0.125f;
    }
    float m = sc;
    for (int o = 32; o > 0; o >>= 1) m = fmaxf(m, __shfl_xor(m, o));
    int lane = t & 63, wv = t >> 6;
    if (lane == 0) red[wv] = m;
    __syncthreads();
    m = fmaxf(fmaxf(red[0], red[1]), fmaxf(red[2], red[3]));
    float e = (t <= qi) ? expf(sc - m) : 0.f;
    ps[t] = e;
    float sum = e;
    for (int o = 32; o > 0; o >>= 1) sum += __shfl_xor(sum, o);
    if (lane == 0) red2[wv] = sum;
    __syncthreads();
    sum = red2[0] + red2[1] + red2[2] + red2[3];
    float inv = 1.f / sum;
    int d = t & 63, g = t >> 6;
    float acc = 0.f;
    for (int ki = g; ki <= qi; ki += 4)
        acc = fmaf(ps[ki], qkv[(size_t)ki * FF + 2 * DMODEL + h * HD + d], acc);
    os[g][d] = acc * inv;
    __syncthreads();
    if (t < HD)
        out[(size_t)qi * DMODEL + h * HD + t] = os[0][t] + os[1][t] + os[2][t] + os[3][t];
}

// ---------------- halt logits: sigmoid(h . w_halt + b) ----------------
__global__ __launch_bounds__(64) void k_halt(const float* __restrict__ H,
                                             const float* __restrict__ w,
                                             const float* __restrict__ bptr,
                                             float* __restrict__ halt) {
    int s = blockIdx.y, row = blockIdx.x;
    const float* h = H + ((size_t)s * NTOK + row) * DMODEL;
    float acc = 0.f;
    for (int d = threadIdx.x; d < DMODEL; d += 64) acc = fmaf(h[d], w[d], acc);
    for (int o = 32; o > 0; o >>= 1) acc += __shfl_xor(acc, o);
    if (threadIdx.x == 0)
        halt[s * NTOK + row] = 1.f / (1.f + expf(-(acc + bptr[0])));
}

// ---------------- ACT combine weights + ponder ----------------
__global__ void k_act(const float* __restrict__ halt, float* __restrict__ wts,
                      float* __restrict__ ponder_out, float* __restrict__ w_out) {
    int i = threadIdx.x;  // 256 tokens, single block
    float p[4];
#pragma unroll
    for (int s = 0; s < 4; ++s) p[s] = halt[s * NTOK + i];
    p[0] = 0.f;  // MIN_STEPS = 1
    float cum = 0.f, rem = 0.f, w[4];
    int nrun = 0;
#pragma unroll
    for (int s = 0; s < 4; ++s) {
        float prev = cum;
        cum += p[s];
        bool running = prev < THR;
        bool use_rem = running && ((cum >= THR) || (s == 3));
        float v = 0.f;
        if (running) {
            v = use_rem ? (1.f - prev) : p[s];
            if (use_rem) rem += (1.f - prev);
            nrun++;
        }
        w[s] = v;
    }
#pragma unroll
    for (int s = 0; s < 4; ++s) { wts[i * 4 + s] = w[s]; w_out[i * 4 + s] = w[s]; }
    ponder_out[i] = (float)nrun + rem;
}

// ---------------- A = sum_s w_s * H_s ; B = sum_s w_s * H_{s+1} (bf16 out) ----------------
__global__ void k_ab(const float* __restrict__ H, const float* __restrict__ wts,
                     __hip_bfloat16* __restrict__ A, __hip_bfloat16* __restrict__ Bm) {
    int i = blockIdx.x;
    float w0 = wts[i * 4 + 0], w1 = wts[i * 4 + 1], w2 = wts[i * 4 + 2], w3 = wts[i * 4 + 3];
    for (int d = threadIdx.x; d < DMODEL; d += 256) {
        size_t base = (size_t)i * DMODEL + d;
        float h0 = H[base], h1 = H[base + NTOK * DMODEL], h2 = H[base + 2 * NTOK * DMODEL];
        float h3 = H[base + 3 * (size_t)NTOK * DMODEL], h4 = H[base + 4 * (size_t)NTOK * DMODEL];
        A[base]  = __float2bfloat16(w0 * h0 + w1 * h1 + w2 * h2 + w3 * h3);
        Bm[base] = __float2bfloat16(w0 * h1 + w1 * h2 + w2 * h3 + w3 * h4);
    }
}

// ---------------- final logits via MFMA: out = A @ Wy + B @ Wd ----------------
// Block = 4 waves, each wave owns 16 cols; block owns 64 cols x all 256 rows.
// Weights (f32, HBM) are read exactly once and converted to bf16 in-register.
__global__ __launch_bounds__(256) void k_logits_mfma(const __hip_bfloat16* __restrict__ Abf,
                                                     const __hip_bfloat16* __restrict__ Bbf,
                                                     const float* __restrict__ Wy,
                                                     const float* __restrict__ Wd,
                                                     float* __restrict__ out) {
    const int wave = threadIdx.x >> 6;
    const int lane = threadIdx.x & 63;
    const int col = blockIdx.x * 64 + wave * 16 + (lane & 15);  // this lane's output col
    const int kg = lane >> 4;                                   // k-group 0..3

    f32x4 acc[16];
#pragma unroll
    for (int i = 0; i < 16; ++i) acc[i] = (f32x4){0.f, 0.f, 0.f, 0.f};

    for (int k0 = 0; k0 < DMODEL; k0 += 32) {
        // weight fragments: W[k0 + kg*8 + j][col], j=0..7, converted f32->bf16 (RNE)
        const float* py = Wy + (size_t)(k0 + kg * 8) * VOCAB + col;
        const float* pd = Wd + (size_t)(k0 + kg * 8) * VOCAB + col;
        bf16x8 wy, wd;
#pragma unroll
        for (int j = 0; j < 8; ++j) {
            wy[j] = (short)__hip_bfloat16_raw(__float2bfloat16(py[(size_t)j * VOCAB])).x;
            wd[j] = (short)__hip_bfloat16_raw(__float2bfloat16(pd[(size_t)j * VOCAB])).x;
        }
#pragma unroll
        for (int mt = 0; mt < 16; ++mt) {
            const bf16x8 a = *(const bf16x8*)(Abf + (size_t)(mt * 16 + (lane & 15)) * DMODEL + k0 + kg * 8);
            const bf16x8 b = *(const bf16x8*)(Bbf + (size_t)(mt * 16 + (lane & 15)) * DMODEL + k0 + kg * 8);
            acc[mt] = __builtin_amdgcn_mfma_f32_16x16x32_bf16(a, wy, acc[mt], 0, 0, 0);
            acc[mt] = __builtin_amdgcn_mfma_f32_16x16x32_bf16(b, wd, acc[mt], 0, 0, 0);
        }
    }
    // C/D layout: col = lane&15, row = (lane>>4)*4 + r  [within each 16-row tile]
#pragma unroll
    for (int mt = 0; mt < 16; ++mt)
#pragma unroll
        for (int r = 0; r < 4; ++r)
            out[(size_t)(mt * 16 + kg * 4 + r) * VOCAB + col] = acc[mt][r];
}

extern "C" void kernel_launch(void* const* d_in, const int* in_sizes, int n_in,
                              void* d_out, int out_size, void* d_ws, size_t ws_size,
                              hipStream_t stream) {
    const int*   ids          = (const int*)d_in[0];
    const float* emb          = (const float*)d_in[1];
    const float* attn_norm_w  = (const float*)d_in[2];
    const float* mlp_norm_w   = (const float*)d_in[3];
    const float* wqkv         = (const float*)d_in[4];
    const float* wo           = (const float*)d_in[5];
    const float* w_gate       = (const float*)d_in[6];
    const float* w_up         = (const float*)d_in[7];
    const float* w_down       = (const float*)d_in[8];
    const float* final_norm_w = (const float*)d_in[9];
    const float* rc_norm_w    = (const float*)d_in[10];
    const float* rc_w1        = (const float*)d_in[11];
    const float* rc_w2        = (const float*)d_in[12];
    const float* w_y          = (const float*)d_in[13];
    const float* w_delta      = (const float*)d_in[14];
    const float* w_halt       = (const float*)d_in[15];
    const float* b_halt       = (const float*)d_in[16];
    float* out = (float*)d_out;

    float* ws = (float*)d_ws;
    float* x       = ws + 0;         // 131072
    float* xn      = ws + 131072;    // 131072
    float* qkv     = ws + 262144;    // 393216
    float* attnout = ws + 655360;    // 131072
    float* g       = ws + 786432;    // 393216
    float* t1      = ws + 1179648;   // 524288 (rc mlp intermediate; also Cp2 in backbone)
    float* states  = ws + 1703936;   // 131072
    float* states2 = ws + 1835008;   // 131072
    float* H       = ws + 1966080;   // 655360 (5 slices of 131072)
    float* haltb   = ws + 2621440;   // 1024
    float* wts     = ws + 2622464;   // 1024
    __hip_bfloat16* Abf = (__hip_bfloat16*)(ws + 2623488);   // 256KB (131072 bf16)
    __hip_bfloat16* Bbf = (__hip_bfloat16*)(ws + 2754560);   // 256KB
    float* Cp      = ws + 2885632;   // 2097152 (split-K partials)
    float* Cp2     = t1;             // alias: gate/up partials live only in backbone

    auto mm = [&](const float* A, const float* W, const float* res, float* C,
                  int K, int N, int nsplit, int act) {
        int kc = K / nsplit;
        k_mm_part<<<dim3(N / 64, NTOK / 64, nsplit), 256, 0, stream>>>(A, W, Cp, K, N, kc);
        int tot = NTOK * N;
        k_mm_finish<<<(tot + 255) / 256, 256, 0, stream>>>(Cp, res, C, tot, tot, nsplit, act);
    };

    // ---------- backbone ----------
    k_embed<<<NTOK, 256, 0, stream>>>(ids, emb, x);
    for (int l = 0; l < NLAYER; ++l) {
        k_rmsnorm<<<NTOK, 256, 0, stream>>>(x, attn_norm_w + l * DMODEL, xn);
        mm(xn, wqkv + (size_t)l * DMODEL * FF, nullptr, qkv, DMODEL, FF, 2, 0);
        k_rope<<<NTOK, 256, 0, stream>>>(qkv);
        k_attn<<<dim3(NHEAD, NTOK), 256, 0, stream>>>(qkv, attnout);
        mm(attnout, wo + (size_t)l * DMODEL * DMODEL, x, x, DMODEL, DMODEL, 2, 0);
        k_rmsnorm<<<NTOK, 256, 0, stream>>>(x, mlp_norm_w + l * DMODEL, xn);
        {
            int kc = DMODEL / 2;
            k_mm_part<<<dim3(FF / 64, NTOK / 64, 2), 256, 0, stream>>>(
                xn, w_gate + (size_t)l * DMODEL * FF, Cp, DMODEL, FF, kc);
            k_mm_part<<<dim3(FF / 64, NTOK / 64, 2), 256, 0, stream>>>(
                xn, w_up + (size_t)l * DMODEL * FF, Cp2, DMODEL, FF, kc);
            int tot = NTOK * FF;
            k_finish_silumul<<<(tot + 255) / 256, 256, 0, stream>>>(Cp, Cp2, g, tot, tot, 2);
        }
        mm(g, w_down + (size_t)l * FF * DMODEL, x, x, FF, DMODEL, 3, 0);
    }
    k_rmsnorm<<<NTOK, 256, 0, stream>>>(x, final_norm_w, states);

    // ---------- refinement steps (halt path stays f32) ----------
    float* scur = states;
    float* snxt = states2;
    for (int s = 0; s < NSTEPS; ++s) {
        k_rmsnorm<<<NTOK, 256, 0, stream>>>(scur, rc_norm_w, H + (size_t)s * NTOK * DMODEL);
        mm(H + (size_t)s * NTOK * DMODEL, rc_w1, nullptr, t1, DMODEL, RCFF, 2, 1);  // gelu fused
        mm(t1, rc_w2, scur, snxt, RCFF, DMODEL, 4, 0);
        float* tmp = scur; scur = snxt; snxt = tmp;
    }
    k_rmsnorm<<<NTOK, 256, 0, stream>>>(scur, rc_norm_w, H + (size_t)NSTEPS * NTOK * DMODEL);

    // ---------- halt, ACT weights, A/B combine (bf16) ----------
    k_halt<<<dim3(NTOK, NSTEPS), 64, 0, stream>>>(H, w_halt, b_halt, haltb);
    k_act<<<1, 256, 0, stream>>>(haltb, wts, out + (size_t)NTOK * VOCAB,
                                 out + (size_t)NTOK * VOCAB + NTOK);
    k_ab<<<NTOK, 256, 0, stream>>>(H, wts, Abf, Bbf);

    // ---------- final logits (MFMA bf16, weights streamed once) ----------
    k_logits_mfma<<<VOCAB / 64, 256, 0, stream>>>(Abf, Bbf, w_y, w_delta, out);
}

// Round 4
// 531.541 us; speedup vs baseline: 1.4418x; 1.2347x over previous
//
#include <hip/hip_runtime.h>
#include <hip/hip_bf16.h>

#define NTOK   256
#define DMODEL 512
#define NHEAD  8
#define HD     64
#define HALF   32
#define FF     1536
#define RCFF   2048
#define VOCAB  32000
#define NLAYER 2
#define NSTEPS 4
#define EPSV   1e-6f
#define THR    0.99f

typedef __attribute__((ext_vector_type(8))) short bf16x8;
typedef __attribute__((ext_vector_type(4))) float f32x4;

// ---------------- embedding gather ----------------
__global__ void k_embed(const int* __restrict__ ids, const float* __restrict__ emb,
                        float* __restrict__ x) {
    int row = blockIdx.x;
    int id = ids[row];
    for (int d = threadIdx.x; d < DMODEL; d += blockDim.x)
        x[row * DMODEL + d] = emb[(size_t)id * DMODEL + d];
}

// ---------------- rmsnorm (one block per row) ----------------
__global__ __launch_bounds__(256) void k_rmsnorm(const float* __restrict__ in,
                                                 const float* __restrict__ w,
                                                 float* __restrict__ out) {
    int row = blockIdx.x;
    const float* xr = in + (size_t)row * DMODEL;
    float s = 0.f;
    for (int d = threadIdx.x; d < DMODEL; d += 256) { float v = xr[d]; s += v * v; }
    __shared__ float red[4];
    int lane = threadIdx.x & 63, wv = threadIdx.x >> 6;
    for (int o = 32; o > 0; o >>= 1) s += __shfl_xor(s, o);
    if (lane == 0) red[wv] = s;
    __syncthreads();
    float tot = red[0] + red[1] + red[2] + red[3];
    float scale = rsqrtf(tot * (1.f / DMODEL) + EPSV);
    for (int d = threadIdx.x; d < DMODEL; d += 256)
        out[(size_t)row * DMODEL + d] = xr[d] * scale * w[d];
}

// ---------------- split-K matmul partial ----------------
__global__ __launch_bounds__(256) void k_mm_part(const float* __restrict__ A,
                                                 const float* __restrict__ W,
                                                 float* __restrict__ Cp,
                                                 int K, int N, int kc) {
    __shared__ float As[16][68];
    __shared__ float Ws[16][68];
    const int bn = blockIdx.x * 64;
    const int bm = blockIdx.y * 64;
    const int kz = blockIdx.z * kc;
    const int tx = threadIdx.x & 15;
    const int ty = threadIdx.x >> 4;
    float acc[4][4] = {};
    for (int k0 = kz; k0 < kz + kc; k0 += 16) {
#pragma unroll
        for (int r = 0; r < 4; ++r) {
            int idx = threadIdx.x + r * 256;
            int m = idx >> 4, kk = idx & 15;
            As[kk][m] = A[(size_t)(bm + m) * K + k0 + kk];
            int n = idx & 63, kw = idx >> 6;
            Ws[kw][n] = W[(size_t)(k0 + kw) * N + bn + n];
        }
        __syncthreads();
#pragma unroll
        for (int kk = 0; kk < 16; ++kk) {
            float4 av = *(const float4*)&As[kk][ty * 4];
            float4 bv = *(const float4*)&Ws[kk][tx * 4];
            float a[4] = {av.x, av.y, av.z, av.w};
            float b[4] = {bv.x, bv.y, bv.z, bv.w};
#pragma unroll
            for (int i = 0; i < 4; ++i)
#pragma unroll
                for (int j = 0; j < 4; ++j)
                    acc[i][j] = fmaf(a[i], b[j], acc[i][j]);
        }
        __syncthreads();
    }
    float* cp = Cp + (size_t)blockIdx.z * (size_t)(gridDim.y * 64) * N;
#pragma unroll
    for (int i = 0; i < 4; ++i) {
        int m = bm + ty * 4 + i;
#pragma unroll
        for (int j = 0; j < 4; ++j)
            cp[(size_t)m * N + bn + tx * 4 + j] = acc[i][j];
    }
}

// ---------------- split-K reduce (+residual, +optional gelu) ----------------
__global__ void k_mm_finish(const float* __restrict__ Cp, const float* __restrict__ res,
                            float* __restrict__ C, int tot, int zstride, int nz, int act) {
    int i = blockIdx.x * 256 + threadIdx.x;
    if (i >= tot) return;
    float s = 0.f;
    for (int z = 0; z < nz; ++z) s += Cp[(size_t)z * zstride + i];
    if (res) s += res[i];
    if (act == 1) {  // gelu (tanh approx, jax default)
        float xg = s;
        float inner = 0.79788456080286536f * (xg + 0.044715f * xg * xg * xg);
        s = 0.5f * xg * (1.f + tanhf(inner));
    }
    C[i] = s;
}

// ---------------- split-K reduce for gate/up with silu(g)*u fusion ----------------
__global__ void k_finish_silumul(const float* __restrict__ Gp, const float* __restrict__ Up,
                                 float* __restrict__ C, int tot, int zstride, int nz) {
    int i = blockIdx.x * 256 + threadIdx.x;
    if (i >= tot) return;
    float g = 0.f, u = 0.f;
    for (int z = 0; z < nz; ++z) {
        g += Gp[(size_t)z * zstride + i];
        u += Up[(size_t)z * zstride + i];
    }
    float sig = 1.f / (1.f + expf(-g));
    C[i] = g * sig * u;
}

// ---------------- RoPE in-place on q,k halves of qkv ----------------
__global__ void k_rope(float* __restrict__ qkv) {
    int pos = blockIdx.x;
    int t = threadIdx.x;          // 256 = 8 heads * 32 pairs
    int h = t >> 5, d = t & 31;
    float inv = powf(10000.f, -(float)d / 32.f);
    float ang = (float)pos * inv;
    float c = cosf(ang), s = sinf(ang);
    float* q = qkv + (size_t)pos * FF + h * HD;
    float x1 = q[d], x2 = q[d + HALF];
    q[d] = x1 * c - x2 * s;
    q[d + HALF] = x1 * s + x2 * c;
    float* k = q + DMODEL;
    x1 = k[d]; x2 = k[d + HALF];
    k[d] = x1 * c - x2 * s;
    k[d + HALF] = x1 * s + x2 * c;
}

// ---------------- attention: one block per (head, query) ----------------
__global__ __launch_bounds__(256) void k_attn(const float* __restrict__ qkv,
                                              float* __restrict__ out) {
    int h = blockIdx.x;
    int qi = blockIdx.y;
    int t = threadIdx.x;
    __shared__ float qs[HD];
    __shared__ float ps[NTOK];
    __shared__ float red[4];
    __shared__ float red2[4];
    __shared__ float os[4][HD];
    if (t < HD) qs[t] = qkv[(size_t)qi * FF + h * HD + t];
    __syncthreads();
    float sc = -1e30f;
    if (t <= qi) {
        const float* kr = qkv + (size_t)t * FF + DMODEL + h * HD;
        float s = 0.f;
        for (int d = 0; d < HD; ++d) s = fmaf(qs[d], kr[d], s);
        sc = s * 0.125f;
    }
    float m = sc;
    for (int o = 32; o > 0; o >>= 1) m = fmaxf(m, __shfl_xor(m, o));
    int lane = t & 63, wv = t >> 6;
    if (lane == 0) red[wv] = m;
    __syncthreads();
    m = fmaxf(fmaxf(red[0], red[1]), fmaxf(red[2], red[3]));
    float e = (t <= qi) ? expf(sc - m) : 0.f;
    ps[t] = e;
    float sum = e;
    for (int o = 32; o > 0; o >>= 1) sum += __shfl_xor(sum, o);
    if (lane == 0) red2[wv] = sum;
    __syncthreads();
    sum = red2[0] + red2[1] + red2[2] + red2[3];
    float inv = 1.f / sum;
    int d = t & 63, g = t >> 6;
    float acc = 0.f;
    for (int ki = g; ki <= qi; ki += 4)
        acc = fmaf(ps[ki], qkv[(size_t)ki * FF + 2 * DMODEL + h * HD + d], acc);
    os[g][d] = acc * inv;
    __syncthreads();
    if (t < HD)
        out[(size_t)qi * DMODEL + h * HD + t] = os[0][t] + os[1][t] + os[2][t] + os[3][t];
}

// ---------------- halt logits: sigmoid(h . w_halt + b) ----------------
__global__ __launch_bounds__(64) void k_halt(const float* __restrict__ H,
                                             const float* __restrict__ w,
                                             const float* __restrict__ bptr,
                                             float* __restrict__ halt) {
    int s = blockIdx.y, row = blockIdx.x;
    const float* h = H + ((size_t)s * NTOK + row) * DMODEL;
    float acc = 0.f;
    for (int d = threadIdx.x; d < DMODEL; d += 64) acc = fmaf(h[d], w[d], acc);
    for (int o = 32; o > 0; o >>= 1) acc += __shfl_xor(acc, o);
    if (threadIdx.x == 0)
        halt[s * NTOK + row] = 1.f / (1.f + expf(-(acc + bptr[0])));
}

// ---------------- ACT combine weights + ponder ----------------
__global__ void k_act(const float* __restrict__ halt, float* __restrict__ wts,
                      float* __restrict__ ponder_out, float* __restrict__ w_out) {
    int i = threadIdx.x;  // 256 tokens, single block
    float p[4];
#pragma unroll
    for (int s = 0; s < 4; ++s) p[s] = halt[s * NTOK + i];
    p[0] = 0.f;  // MIN_STEPS = 1
    float cum = 0.f, rem = 0.f, w[4];
    int nrun = 0;
#pragma unroll
    for (int s = 0; s < 4; ++s) {
        float prev = cum;
        cum += p[s];
        bool running = prev < THR;
        bool use_rem = running && ((cum >= THR) || (s == 3));
        float v = 0.f;
        if (running) {
            v = use_rem ? (1.f - prev) : p[s];
            if (use_rem) rem += (1.f - prev);
            nrun++;
        }
        w[s] = v;
    }
#pragma unroll
    for (int s = 0; s < 4; ++s) { wts[i * 4 + s] = w[s]; w_out[i * 4 + s] = w[s]; }
    ponder_out[i] = (float)nrun + rem;
}

// ---------------- A = sum_s w_s * H_s ; B = sum_s w_s * H_{s+1} (bf16 out) ----------------
__global__ void k_ab(const float* __restrict__ H, const float* __restrict__ wts,
                     __hip_bfloat16* __restrict__ A, __hip_bfloat16* __restrict__ Bm) {
    int i = blockIdx.x;
    float w0 = wts[i * 4 + 0], w1 = wts[i * 4 + 1], w2 = wts[i * 4 + 2], w3 = wts[i * 4 + 3];
    for (int d = threadIdx.x; d < DMODEL; d += 256) {
        size_t base = (size_t)i * DMODEL + d;
        float h0 = H[base], h1 = H[base + NTOK * DMODEL], h2 = H[base + 2 * NTOK * DMODEL];
        float h3 = H[base + 3 * (size_t)NTOK * DMODEL], h4 = H[base + 4 * (size_t)NTOK * DMODEL];
        A[base]  = __float2bfloat16(w0 * h0 + w1 * h1 + w2 * h2 + w3 * h3);
        Bm[base] = __float2bfloat16(w0 * h1 + w1 * h2 + w2 * h3 + w3 * h4);
    }
}

// ---------------- final logits via MFMA: out = A @ Wy + B @ Wd ----------------
// 8 waves/block; block owns 64 cols x 256 rows. Weight tiles (32k x 64n, f32)
// are staged through LDS with coalesced float4 loads (converted to bf16),
// register-double-buffered across the MFMA phase. Weights read exactly once.
// LDS pad 70; fragment read MUST include the wave's column group wcol
// (round-3 bug: missing wcol made all waves read columns 0-15).
__global__ __launch_bounds__(512) void k_logits_mfma(const __hip_bfloat16* __restrict__ Abf,
                                                     const __hip_bfloat16* __restrict__ Bbf,
                                                     const float* __restrict__ Wy,
                                                     const float* __restrict__ Wd,
                                                     float* __restrict__ out) {
    __shared__ short Wys[32 * 70];
    __shared__ short Wds[32 * 70];
    const int tid  = threadIdx.x;
    const int wave = tid >> 6;
    const int lane = tid & 63;
    const int wrow = (wave & 1) * 128;        // row half owned by this wave
    const int wcol = (wave >> 1) * 16;        // 16-col group within block's 64
    const int cl   = lane & 15;
    const int kg   = lane >> 4;
    const int col  = blockIdx.x * 64 + wcol + cl;

    // staging coords: 512 threads cover a 32(k) x 64(n) f32 tile, one float4 each
    const int kr = tid >> 4;                  // 0..31
    const int c4 = (tid & 15) * 4;            // 0,4,..,60

    f32x4 acc[8];
#pragma unroll
    for (int i = 0; i < 8; ++i) acc[i] = (f32x4){0.f, 0.f, 0.f, 0.f};

    const float* gy = Wy + (size_t)kr * VOCAB + blockIdx.x * 64 + c4;
    const float* gd = Wd + (size_t)kr * VOCAB + blockIdx.x * 64 + c4;

    float4 ry = *(const float4*)gy;
    float4 rd = *(const float4*)gd;

    for (int t = 0; t < 16; ++t) {
        __syncthreads();  // previous iteration's fragment reads complete
        {
            short2 a, b;
            a.x = (short)__hip_bfloat16_raw(__float2bfloat16(ry.x)).x;
            a.y = (short)__hip_bfloat16_raw(__float2bfloat16(ry.y)).x;
            b.x = (short)__hip_bfloat16_raw(__float2bfloat16(ry.z)).x;
            b.y = (short)__hip_bfloat16_raw(__float2bfloat16(ry.w)).x;
            *(short2*)&Wys[kr * 70 + c4]     = a;
            *(short2*)&Wys[kr * 70 + c4 + 2] = b;
            a.x = (short)__hip_bfloat16_raw(__float2bfloat16(rd.x)).x;
            a.y = (short)__hip_bfloat16_raw(__float2bfloat16(rd.y)).x;
            b.x = (short)__hip_bfloat16_raw(__float2bfloat16(rd.z)).x;
            b.y = (short)__hip_bfloat16_raw(__float2bfloat16(rd.w)).x;
            *(short2*)&Wds[kr * 70 + c4]     = a;
            *(short2*)&Wds[kr * 70 + c4 + 2] = b;
        }
        if (t < 15) {  // prefetch next 32-k tile
            ry = *(const float4*)(gy + (size_t)(t + 1) * 32 * VOCAB);
            rd = *(const float4*)(gd + (size_t)(t + 1) * 32 * VOCAB);
        }
        __syncthreads();  // LDS tile visible
        const int k0 = t * 32;
        bf16x8 wy, wd;
#pragma unroll
        for (int j = 0; j < 8; ++j) {
            wy[j] = Wys[(kg * 8 + j) * 70 + wcol + cl];
            wd[j] = Wds[(kg * 8 + j) * 70 + wcol + cl];
        }
#pragma unroll
        for (int mt = 0; mt < 8; ++mt) {
            const int row = wrow + mt * 16 + cl;
            const bf16x8 a = *(const bf16x8*)(Abf + (size_t)row * DMODEL + k0 + kg * 8);
            const bf16x8 b = *(const bf16x8*)(Bbf + (size_t)row * DMODEL + k0 + kg * 8);
            acc[mt] = __builtin_amdgcn_mfma_f32_16x16x32_bf16(a, wy, acc[mt], 0, 0, 0);
            acc[mt] = __builtin_amdgcn_mfma_f32_16x16x32_bf16(b, wd, acc[mt], 0, 0, 0);
        }
    }
    // C/D layout: col = lane&15, row-in-tile = kg*4 + r
#pragma unroll
    for (int mt = 0; mt < 8; ++mt)
#pragma unroll
        for (int r = 0; r < 4; ++r)
            out[(size_t)(wrow + mt * 16 + kg * 4 + r) * VOCAB + col] = acc[mt][r];
}

extern "C" void kernel_launch(void* const* d_in, const int* in_sizes, int n_in,
                              void* d_out, int out_size, void* d_ws, size_t ws_size,
                              hipStream_t stream) {
    const int*   ids          = (const int*)d_in[0];
    const float* emb          = (const float*)d_in[1];
    const float* attn_norm_w  = (const float*)d_in[2];
    const float* mlp_norm_w   = (const float*)d_in[3];
    const float* wqkv         = (const float*)d_in[4];
    const float* wo           = (const float*)d_in[5];
    const float* w_gate       = (const float*)d_in[6];
    const float* w_up         = (const float*)d_in[7];
    const float* w_down       = (const float*)d_in[8];
    const float* final_norm_w = (const float*)d_in[9];
    const float* rc_norm_w    = (const float*)d_in[10];
    const float* rc_w1        = (const float*)d_in[11];
    const float* rc_w2        = (const float*)d_in[12];
    const float* w_y          = (const float*)d_in[13];
    const float* w_delta      = (const float*)d_in[14];
    const float* w_halt       = (const float*)d_in[15];
    const float* b_halt       = (const float*)d_in[16];
    float* out = (float*)d_out;

    float* ws = (float*)d_ws;
    float* x       = ws + 0;         // 131072
    float* xn      = ws + 131072;    // 131072
    float* qkv     = ws + 262144;    // 393216
    float* attnout = ws + 655360;    // 131072
    float* g       = ws + 786432;    // 393216
    float* t1      = ws + 1179648;   // 524288 (rc mlp intermediate)
    float* states  = ws + 1703936;   // 131072
    float* states2 = ws + 1835008;   // 131072
    float* H       = ws + 1966080;   // 655360 (5 slices of 131072)
    float* haltb   = ws + 2621440;   // 1024
    float* wts     = ws + 2622464;   // 1024
    __hip_bfloat16* Abf = (__hip_bfloat16*)(ws + 2623488);   // 131072 bf16
    __hip_bfloat16* Bbf = (__hip_bfloat16*)(ws + 2754560);   // 131072 bf16
    float* Cp      = ws + 2885632;   // 2097152 floats of split-K partials
    float* Cp2     = Cp + 1048576;   // second half (gate/up partials)

    auto mm = [&](const float* A, const float* W, const float* res, float* C,
                  int K, int N, int nsplit, int act) {
        int kc = K / nsplit;
        k_mm_part<<<dim3(N / 64, NTOK / 64, nsplit), 256, 0, stream>>>(A, W, Cp, K, N, kc);
        int tot = NTOK * N;
        k_mm_finish<<<(tot + 255) / 256, 256, 0, stream>>>(Cp, res, C, tot, tot, nsplit, act);
    };

    // ---------- backbone ----------
    k_embed<<<NTOK, 256, 0, stream>>>(ids, emb, x);
    for (int l = 0; l < NLAYER; ++l) {
        k_rmsnorm<<<NTOK, 256, 0, stream>>>(x, attn_norm_w + l * DMODEL, xn);
        mm(xn, wqkv + (size_t)l * DMODEL * FF, nullptr, qkv, DMODEL, FF, 4, 0);
        k_rope<<<NTOK, 256, 0, stream>>>(qkv);
        k_attn<<<dim3(NHEAD, NTOK), 256, 0, stream>>>(qkv, attnout);
        mm(attnout, wo + (size_t)l * DMODEL * DMODEL, x, x, DMODEL, DMODEL, 8, 0);
        k_rmsnorm<<<NTOK, 256, 0, stream>>>(x, mlp_norm_w + l * DMODEL, xn);
        {
            int kc = DMODEL / 2;
            k_mm_part<<<dim3(FF / 64, NTOK / 64, 2), 256, 0, stream>>>(
                xn, w_gate + (size_t)l * DMODEL * FF, Cp, DMODEL, FF, kc);
            k_mm_part<<<dim3(FF / 64, NTOK / 64, 2), 256, 0, stream>>>(
                xn, w_up + (size_t)l * DMODEL * FF, Cp2, DMODEL, FF, kc);
            int tot = NTOK * FF;
            k_finish_silumul<<<(tot + 255) / 256, 256, 0, stream>>>(Cp, Cp2, g, tot, tot, 2);
        }
        mm(g, w_down + (size_t)l * FF * DMODEL, x, x, FF, DMODEL, 12, 0);
    }
    k_rmsnorm<<<NTOK, 256, 0, stream>>>(x, final_norm_w, states);

    // ---------- refinement steps (halt path stays f32) ----------
    float* scur = states;
    float* snxt = states2;
    for (int s = 0; s < NSTEPS; ++s) {
        k_rmsnorm<<<NTOK, 256, 0, stream>>>(scur, rc_norm_w, H + (size_t)s * NTOK * DMODEL);
        mm(H + (size_t)s * NTOK * DMODEL, rc_w1, nullptr, t1, DMODEL, RCFF, 4, 1);  // gelu fused
        mm(t1, rc_w2, scur, snxt, RCFF, DMODEL, 16, 0);
        float* tmp = scur; scur = snxt; snxt = tmp;
    }
    k_rmsnorm<<<NTOK, 256, 0, stream>>>(scur, rc_norm_w, H + (size_t)NSTEPS * NTOK * DMODEL);

    // ---------- halt, ACT weights, A/B combine (bf16) ----------
    k_halt<<<dim3(NTOK, NSTEPS), 64, 0, stream>>>(H, w_halt, b_halt, haltb);
    k_act<<<1, 256, 0, stream>>>(haltb, wts, out + (size_t)NTOK * VOCAB,
                                 out + (size_t)NTOK * VOCAB + NTOK);
    k_ab<<<NTOK, 256, 0, stream>>>(H, wts, Abf, Bbf);

    // ---------- final logits (MFMA bf16, LDS-staged weights) ----------
    k_logits_mfma<<<VOCAB / 64, 512, 0, stream>>>(Abf, Bbf, w_y, w_delta, out);
}